// Round 16
// baseline (55.015 us; speedup 1.0000x reference)
//
#include <hip/hip_runtime.h>
#include <math.h>

// (N,C,H,W) = (4,19,512,1024), f32 input, scalar f32 output.
// R16: fire-and-forget staging. All prior variants (R2..R15, 44-57us) load
// to REGISTERS: wave progress is chained to vmcnt-ordered load returns, and
// one-shot never reaches the 7.6 TB/s steady stream R9's marginal reps
// showed. The only one-shot 7 TB/s observed on this chip is the fill's
// fire-and-forget stores. global_load_lds (DMA to LDS, width 16) makes the
// load path store-like: issue and move on; wait (counted vmcnt, never 0
// mid-stream) only before READING the LDS chunk, one chunk look-ahead,
// ping-pong buffers, per-wave-private LDS slices -> zero barriers in loop.
#define NC 19
#define NN 4
#define HH 512
#define WW 1024
#define NBLK 1024            // 1024 blocks * 256 thr * 2 tiles * 4 px = Np
#define TILES 2
#define NREP 32              // LDS accumulator replicas (rep = tid & 31)
#define COLS (2 * NC)
#define CSTRIDE 1024         // column stride in ws (== NBLK)
#define WAVES 4

__global__ __launch_bounds__(256) void msiw_pass1(const float* __restrict__ x,
                                                  float* __restrict__ ws) {
    __shared__ float4 s_tile[2][4][WAVES][64];   // 32 KB ping-pong chunk ring
    __shared__ float  s_acc[2][NREP][NC];        // 4.86 KB bins
    const int tid  = threadIdx.x;
    const int wv   = tid >> 6;
    const int lane = tid & 63;
    const int rep  = tid & (NREP - 1);

    for (int i = tid; i < 2 * NREP * NC; i += 256) (&s_acc[0][0][0])[i] = 0.0f;
    __syncthreads();

    const size_t cs = (size_t)HH * WW;           // channel stride (elements)

    float Z[4], Q[4], m[4];
    int   p[4];

    // per-lane pixel base for tile r
    #define BASEPX(r) ({                                                      \
        const int u  = ((blockIdx.x * TILES + (r)) << 8) + tid;               \
        const int w4 = u & 255;                                               \
        const int h  = (u >> 8) & 511;                                        \
        const int n  = u >> 17;                                               \
        ((size_t)(n * NC) * HH + h) * WW + (size_t)w4 * 4; })

    #define CNTK(k) ((k) == 4 ? 3 : 4)

    // Issue chunk S's DMAs (fire-and-forget). LDS dst is wave-uniform base;
    // HW writes base + lane*16. Global src is per-lane.
    #define ISSUE(S) {                                                        \
        const size_t bp_ = BASEPX((S) / 5);                                   \
        _Pragma("unroll")                                                     \
        for (int c = 0; c < CNTK((S) % 5); ++c) {                             \
            const float* src_ = x + bp_ + (size_t)(((S) % 5) * 4 + c) * cs;   \
            __builtin_amdgcn_global_load_lds(                                 \
                (const __attribute__((address_space(1))) unsigned int*)src_,  \
                (__attribute__((address_space(3))) unsigned int*)              \
                    &s_tile[(S) & 1][c][wv][0],                               \
                16, 0, 0);                                                    \
        } }

    #define UPD(xv, j, ch) {                                                  \
        const float e_ = __expf(xv);                                          \
        if ((ch) == 0) { Z[j] = e_; Q[j] = e_ * e_; m[j] = (xv); p[j] = 0; }   \
        else { Z[j] += e_; Q[j] = fmaf(e_, e_, Q[j]);                         \
               if ((xv) > m[j]) { m[j] = (xv); p[j] = (ch); } } }

    #define COMPUTE(S) {                                                      \
        _Pragma("unroll")                                                     \
        for (int c = 0; c < CNTK((S) % 5); ++c) {                             \
            const float4 v_  = s_tile[(S) & 1][c][wv][lane];                  \
            const int    ch_ = ((S) % 5) * 4 + c;                             \
            UPD(v_.x, 0, ch_) UPD(v_.y, 1, ch_)                               \
            UPD(v_.z, 2, ch_) UPD(v_.w, 3, ch_)                               \
        } }

    #define FINTILE() {                                                       \
        _Pragma("unroll")                                                     \
        for (int j = 0; j < 4; ++j) {                                         \
            atomicAdd(&s_acc[0][rep][p[j]], Q[j] / (Z[j] * Z[j]));            \
            atomicAdd(&s_acc[1][rep][p[j]], 1.0f);                            \
        } }

    // counted waitcnt (never 0 mid-stream) + fence against ds_read hoisting
    #define WAITV(STR) asm volatile("s_waitcnt " STR ::: "memory");           \
                       __builtin_amdgcn_sched_barrier(0);

    // 2 tiles x 5 chunks = 10 steps; issue S+1, wait for S, compute S.
    ISSUE(0)
    ISSUE(1) WAITV("vmcnt(4)") COMPUTE(0)
    ISSUE(2) WAITV("vmcnt(4)") COMPUTE(1)
    ISSUE(3) WAITV("vmcnt(4)") COMPUTE(2)
    ISSUE(4) WAITV("vmcnt(3)") COMPUTE(3)
    ISSUE(5) WAITV("vmcnt(4)") COMPUTE(4) FINTILE()
    ISSUE(6) WAITV("vmcnt(4)") COMPUTE(5)
    ISSUE(7) WAITV("vmcnt(4)") COMPUTE(6)
    ISSUE(8) WAITV("vmcnt(4)") COMPUTE(7)
    ISSUE(9) WAITV("vmcnt(3)") COMPUTE(8)
             WAITV("vmcnt(0)") COMPUTE(9) FINTILE()

    __syncthreads();
    // Flush 38 per-block partials, column-major: ws[col*NBLK + block].
    // Kernel boundary provides the device-scope release.
    if (tid < COLS) {
        const int a = (tid < NC) ? 0 : 1;
        const int c = (tid < NC) ? tid : (tid - NC);
        float acc = 0.0f;
        #pragma unroll
        for (int rp = 0; rp < NREP; ++rp) acc += s_acc[a][rp][c];
        ws[(size_t)tid * CSTRIDE + blockIdx.x] = acc;
    }
}

// 16 waves: wave w reduces columns w, w+16, w+32; float4 batched loads.
__global__ __launch_bounds__(1024) void msiw_pass2(const float* __restrict__ ws,
                                                   float* __restrict__ out) {
    __shared__ float s_col[COLS];
    const int tid  = threadIdx.x;
    const int wv   = tid >> 6;       // 0..15
    const int lane = tid & 63;

    for (int col = wv; col < COLS; col += 16) {
        const float4* q = reinterpret_cast<const float4*>(ws + (size_t)col * CSTRIDE);
        float4 a[4];
        #pragma unroll
        for (int i = 0; i < 4; ++i) a[i] = q[lane + i * 64];   // 256 float4 = 1024 f
        float acc = 0.0f;
        #pragma unroll
        for (int i = 0; i < 4; ++i) acc += (a[i].x + a[i].y) + (a[i].z + a[i].w);
        #pragma unroll
        for (int off = 32; off > 0; off >>= 1) acc += __shfl_down(acc, off);
        if (lane == 0) s_col[col] = acc;
    }
    __syncthreads();

    if (tid == 0) {
        const double np_pow = pow((double)NN * HH * WW, 0.8);   // Np^(1-iw)
        double total = 0.0;
        for (int c = 0; c < NC; ++c) {
            double den = pow((double)s_col[NC + c], 0.2) * np_pow;
            if (den < 1.0) den = 1.0;
            total += (double)s_col[c] / den;
        }
        out[0] = (float)(-total / (double)(NN * NC));
    }
}

extern "C" void kernel_launch(void* const* d_in, const int* in_sizes, int n_in,
                              void* d_out, int out_size, void* d_ws, size_t ws_size,
                              hipStream_t stream) {
    const float* x = (const float*)d_in[0];
    float* ws = (float*)d_ws;                 // 38 cols * 1024 floats = 156 KB
    float* out = (float*)d_out;

    msiw_pass1<<<NBLK, 256, 0, stream>>>(x, ws);
    msiw_pass2<<<1, 1024, 0, stream>>>(ws, out);
}

// Round 17
// 47.553 us; speedup vs baseline: 1.1569x; 1.1569x over previous
//
#include <hip/hip_runtime.h>
#include <math.h>

// (N,C,H,W) = (4,19,512,1024), f32 input, scalar f32 output.
// R17 change (single variable vs R12): pipeline depth 2 -> 3 (two tiles'
// loads in flight during every compute). Ledger: R12 one-shot (38.5us) ==
// its own steady rate (R13 marginal 42us) -> no fixed overhead left, just a
// slow steady state. R9's fast steady state (21us/rep) differed from R13's
// (42) in BYTES IN FLIGHT PER WAVE during compute (19KB vs 9.5KB). Depth-3
// doubles R12's in-flight bytes at identical grid/width/occupancy-supply.
#define NC 19
#define NN 4
#define HH 512
#define WW 1024
#define NBLK 512             // 512 blocks * 256 thr * 8 tiles * 2 px = Np
#define TILES 8
#define NREP 32              // LDS accumulator replicas (rep = tid & 31)
#define COLS (2 * NC)        // 19 ssum cols + 19 hist cols
#define CSTRIDE 512          // column stride in ws (== NBLK)

typedef float floatx2 __attribute__((ext_vector_type(2)));

__global__ __launch_bounds__(256) void msiw_pass1(const float* __restrict__ x,
                                                  float* __restrict__ ws) {
    __shared__ float s_acc[2][NREP][NC];   // [0]=ssum, [1]=count (float, exact)
    const int tid = threadIdx.x;

    for (int i = tid; i < 2 * NREP * NC; i += 256) (&s_acc[0][0][0])[i] = 0.0f;
    __syncthreads();

    const size_t cs = (size_t)HH * WW;     // channel stride (elements)
    const int rep = tid & (NREP - 1);      // <=2-way same-address alias (free)

    float buf[3][NC][2];                   // depth-3 ring, static indices only

    #define TILE_BASE(r) ({                                                   \
        const int u    = (blockIdx.x * TILES + (r)) * 256 + tid;              \
        const int w2   = u & 511;              /* W/2 = 512 */                \
        const int rest = u >> 9;                                              \
        const int h    = rest & 511;                                          \
        const int n    = rest >> 9;                                           \
        ((size_t)(n * NC) * HH + h) * WW + (size_t)w2 * 2; })

    #define LOAD_TILE(r, B)                                                   \
        {                                                                     \
            const size_t base_ = TILE_BASE(r);                                \
            _Pragma("unroll")                                                 \
            for (int c = 0; c < NC; ++c) {                                    \
                const floatx2* p2 = reinterpret_cast<const floatx2*>(         \
                    x + base_ + (size_t)c * cs);                              \
                const floatx2 v = *p2;                                        \
                buf[B][c][0] = v.x; buf[B][c][1] = v.y;                       \
            }                                                                 \
        }

    #define COMPUTE_TILE(B)                                                   \
        {                                                                     \
            float Z0 = 0.f, Z1 = 0.f, Q0 = 0.f, Q1 = 0.f;                     \
            float m0 = buf[B][0][0], m1 = buf[B][0][1];                       \
            int   p0 = 0, p1 = 0;                                             \
            _Pragma("unroll")                                                 \
            for (int c = 0; c < NC; ++c) {                                    \
                const float x0 = buf[B][c][0], x1 = buf[B][c][1];             \
                const float e0 = __expf(x0), e1 = __expf(x1);                 \
                Z0 += e0; Z1 += e1;                                           \
                Q0 = fmaf(e0, e0, Q0); Q1 = fmaf(e1, e1, Q1);                 \
                if (c > 0) {                                                  \
                    if (x0 > m0) { m0 = x0; p0 = c; }                         \
                    if (x1 > m1) { m1 = x1; p1 = c; }                         \
                }                                                             \
            }                                                                 \
            atomicAdd(&s_acc[0][rep][p0], Q0 / (Z0 * Z0));                    \
            atomicAdd(&s_acc[1][rep][p0], 1.0f);                              \
            atomicAdd(&s_acc[0][rep][p1], Q1 / (Z1 * Z1));                    \
            atomicAdd(&s_acc[1][rep][p1], 1.0f);                              \
        }

    // Depth-3 software pipeline: two tiles' loads outstanding during every
    // compute. Fully unrolled -> ring indices are compile-time constants.
    LOAD_TILE(0, 0);
    LOAD_TILE(1, 1);
    asm volatile("" ::: "memory");
    #pragma unroll
    for (int r = 0; r < TILES; ++r) {
        if (r + 2 < TILES) {
            LOAD_TILE(r + 2, (r + 2) % 3);
            asm volatile("" ::: "memory");
        }
        COMPUTE_TILE(r % 3);
    }

    __syncthreads();
    // Flush 38 per-block partials, column-major: ws[col*NBLK + block].
    // Kernel boundary provides the device-scope release (no fence needed).
    if (tid < COLS) {
        const int a = (tid < NC) ? 0 : 1;
        const int c = (tid < NC) ? tid : (tid - NC);
        float acc = 0.0f;
        #pragma unroll
        for (int rp = 0; rp < NREP; ++rp) acc += s_acc[a][rp][c];
        ws[(size_t)tid * CSTRIDE + blockIdx.x] = acc;
    }
}

// 16 waves: wave w reduces columns w, w+16, w+32; float4 batched loads.
__global__ __launch_bounds__(1024) void msiw_pass2(const float* __restrict__ ws,
                                                   float* __restrict__ out) {
    __shared__ float s_col[COLS];
    const int tid  = threadIdx.x;
    const int wv   = tid >> 6;       // 0..15
    const int lane = tid & 63;

    for (int col = wv; col < COLS; col += 16) {
        const float4* q = reinterpret_cast<const float4*>(ws + (size_t)col * CSTRIDE);
        float4 a[2];
        #pragma unroll
        for (int i = 0; i < 2; ++i) a[i] = q[lane + i * 64];   // 128 float4 = 512 f
        float acc = 0.0f;
        #pragma unroll
        for (int i = 0; i < 2; ++i) acc += (a[i].x + a[i].y) + (a[i].z + a[i].w);
        #pragma unroll
        for (int off = 32; off > 0; off >>= 1) acc += __shfl_down(acc, off);
        if (lane == 0) s_col[col] = acc;
    }
    __syncthreads();

    if (tid == 0) {
        const double np_pow = pow((double)NN * HH * WW, 0.8);   // Np^(1-iw)
        double total = 0.0;
        for (int c = 0; c < NC; ++c) {
            double den = pow((double)s_col[NC + c], 0.2) * np_pow;
            if (den < 1.0) den = 1.0;
            total += (double)s_col[c] / den;
        }
        out[0] = (float)(-total / (double)(NN * NC));
    }
}

extern "C" void kernel_launch(void* const* d_in, const int* in_sizes, int n_in,
                              void* d_out, int out_size, void* d_ws, size_t ws_size,
                              hipStream_t stream) {
    const float* x = (const float*)d_in[0];
    float* ws = (float*)d_ws;                 // 38 cols * 512 floats = 78 KB
    float* out = (float*)d_out;

    msiw_pass1<<<NBLK, 256, 0, stream>>>(x, ws);
    msiw_pass2<<<1, 1024, 0, stream>>>(ws, out);
}